// Round 12
// baseline (261.978 us; speedup 1.0000x reference)
//
#include <hip/hip_runtime.h>
#include <math.h>
#include <float.h>

// Problem dims (fixed by setup_inputs)
#define BB 32
#define TT 2048
#define OO 128
#define CC 80
#define EPSF 1e-7f
#define NT 256
#define SLOTS 8           // columns per thread in LSA
#define CPAD 81           // LDS class-row stride: 81%32=17, gcd(17,32)=1 -> conflict-free
#define TPT 128           // tokens per cost tile
#define NTILE 16          // cost t-tiles (TT/TPT)

typedef float vf4 __attribute__((ext_vector_type(4)));   // native vec for nontemporal

struct alignas(16) URow { double u; int row; int pad; };   // {u[row4col[j]], row4col[j]}
struct alignas(8)  P2   { int i; int j; };                 // path row, its prior column
struct alignas(16) Cand { double v; double u; int j; int row; };  // +urow folded in

// DPP lexicographic-min (val,idx): incoming lanes aggregate strictly-lower
// column ranges -> (tv <= bv) == first-index tie-break. Identity {+inf, MAX}.
template<int CTRL>
__device__ __forceinline__ void dpp_lexmin(double& bv, int& bj) {
    int lo = __double2loint(bv), hi = __double2hiint(bv);
    int tlo = __builtin_amdgcn_update_dpp(0, lo, CTRL, 0xF, 0xF, false);
    int thi = __builtin_amdgcn_update_dpp(0x7FF00000, hi, CTRL, 0xF, 0xF, false);
    int tj  = __builtin_amdgcn_update_dpp(0x7FFFFFFF, bj, CTRL, 0xF, 0xF, false);
    double tv = __hiloint2double(thi, tlo);
    if (tv <= bv) { bv = tv; bj = tj; }
}

// f32 (val,idx) lexmin for the cost phase's row-min reduction.
template<int CTRL>
__device__ __forceinline__ void dpp_lexmin_f32(float& bv, int& bj) {
    int tlo = __builtin_amdgcn_update_dpp(0x7F800000, __float_as_int(bv), CTRL, 0xF, 0xF, false);
    int tj  = __builtin_amdgcn_update_dpp(0x7FFFFFFF, bj, CTRL, 0xF, 0xF, false);
    float tv = __int_as_float(tlo);
    if (tv < bv || (tv == bv && tj < bj)) { bv = tv; bj = tj; }
}

// LDS is phase-exclusive: cost staging first, LSA state after.
// Union max ~69 KB -> 2 blocks/CU (the occupancy lever for the cost phase).
union SM {
    struct {
        float  xv[TPT * CPAD];                     // 41472 B
        float4 box[OO];                            // {x1,y1,x2,y2}
        float2 wt[OO];                             // {w2h2, tc-as-float-bits}
        unsigned long long rmin[OO * 2];
    } c;
    struct {
        URow   urow[TT];
        P2     path2[TT];                          // swizzled
        int    row4col[TT];
        int    claim[TT];
        int    col4row[OO];
        double u[OO];
        int    amin[OO];
        int    flag[OO];
        int    freelist[OO];
        int    selj[OO + 8];
        double selm[OO + 8];
        int    selrow[OO + 8];
        Cand   cand[2][4];
        int    nfree;
    } l;
};

// ---------------------------------------------------------------------------
// Fused kernel, XCD-matched mapping: b = bx&31, tile = bx>>5 (all of batch
// b's blocks share bx%8 -> same XCD under round-robin). 512 producer blocks
// each do a 128-token cost tile (2 threads/token); tile-0 blocks then
// acquire-spin on cnt[b]==16 and run the JV LSA (greedy tight pre-assignment
// + Dijkstra SAP with pre-barrier urow fold-in and speculative row prefetch).
// ---------------------------------------------------------------------------
__global__ __launch_bounds__(NT) void hung_fused_kernel(
    const float* __restrict__ pb, const float* __restrict__ tb,
    const float* __restrict__ cls, const int* __restrict__ tcls,
    float* __restrict__ cost, unsigned long long* __restrict__ rowmins,
    int* __restrict__ cnt, int* __restrict__ out) {
#pragma clang fp contract(off)
    __shared__ SM sm;

    int bx = blockIdx.x;
    int b = bx & 31;
    int tile = bx >> 5;
    int t0 = tile * TPT;
    int tid = threadIdx.x;
    int lane = tid & 63;
    int wave = tid >> 6;
    int tok = tid & (TPT - 1);
    int oh = tid >> 7;           // o-half: 0 -> o in [0,64), 1 -> [64,128)

    // ======================= Phase 1: cost tile =======================
    {
        // stage class tile (nontemporal: read-once)
        const float* cbase = cls + ((size_t)b * TT + t0) * CC;
        #pragma unroll
        for (int k = 0; k < (TPT * CC) / (NT * 4); ++k) {   // 10 iters
            int idx4 = (k * NT + tid) * 4;
            vf4 vv = __builtin_nontemporal_load((const vf4*)(cbase + idx4));
            int r = idx4 / CC;
            int c = idx4 - r * CC;
            float* dst = &sm.c.xv[r * CPAD + c];
            dst[0] = vv.x; dst[1] = vv.y; dst[2] = vv.z; dst[3] = vv.w;
        }
        if (tid < OO) {
            float4 tbox = ((const float4*)tb)[b * OO + tid];
            float x1 = tbox.x - tbox.z / 2.f;
            float y1 = tbox.y - tbox.w / 2.f;
            float x2 = tbox.x + tbox.z / 2.f;
            float y2 = tbox.y + tbox.w / 2.f;
            float4 bb; bb.x = x1; bb.y = y1; bb.z = x2; bb.w = y2;
            sm.c.box[tid] = bb;
            float w2 = x2 - x1;
            float h2 = (y2 - y1) + EPSF;
            float2 wt; wt.x = w2 * h2;
            wt.y = __int_as_float(tcls[b * OO + tid]);
            sm.c.wt[tid] = wt;
        }
        __syncthreads();

        size_t bt = (size_t)b * TT + t0 + tok;
        float4 pbox = ((const float4*)pb)[bt];
        float b1x1 = pbox.x - pbox.z / 2.f;
        float b1y1 = pbox.y - pbox.w / 2.f;
        float b1x2 = pbox.x + pbox.z / 2.f;
        float b1y2 = pbox.y + pbox.w / 2.f;
        float w1 = b1x2 - b1x1;
        float h1 = (b1y2 - b1y1) + EPSF;
        float w1h1 = w1 * h1;

        // softmax normalizers (sequential op order -> bit-identical to ref)
        const float* xr = &sm.c.xv[tok * CPAD];
        float m = xr[0];
        #pragma unroll
        for (int c = 1; c < CC; ++c) m = fmaxf(m, xr[c]);
        float ssum = 0.f;
        #pragma unroll
        for (int c = 0; c < CC; ++c) ssum += expf(xr[c] - m);
        float ls = logf(ssum);

        float* cbt = cost + (size_t)b * OO * TT + t0;
        for (int k = 0; k < OO / 2; ++k) {
            int o = oh * (OO / 2) + k;
            float4 bb = sm.c.box[o];        // one b128 broadcast per wave
            float2 wt = sm.c.wt[o];
            float b2x1 = bb.x, b2y1 = bb.y, b2x2 = bb.z, b2y2 = bb.w;
            float iw = fminf(b1x2, b2x2) - fmaxf(b1x1, b2x1);
            float ih = fminf(b1y2, b2y2) - fmaxf(b1y1, b2y1);
            iw = fmaxf(iw, 0.f);
            ih = fmaxf(ih, 0.f);
            float inter = iw * ih;
            float uni = ((w1h1 + wt.x) - inter) + EPSF;
            float iou = inter / uni;
            float cw = fmaxf(b1x2, b2x2) - fminf(b1x1, b2x1);
            float ch = fmaxf(b1y2, b2y2) - fminf(b1y1, b2y1);
            float c_area = (cw * ch) + EPSF;
            float giou = iou - (c_area - uni) / c_area;
            float bbox_loss = 1.0f - giou;

            float xc = xr[__float_as_int(wt.y)];   // conflict-free (stride 81)
            float shifted = xc - m;
            float cls_neg = -(shifted - ls);

            float cval = bbox_loss + cls_neg;
            cbt[(size_t)o * TT + tok] = cval;

            // per-(b,o) wave min/argmin over this wave's 64 tokens
            float bvv = cval;
            int bjj = t0 + tok;
            dpp_lexmin_f32<0x111>(bvv, bjj);
            dpp_lexmin_f32<0x112>(bvv, bjj);
            dpp_lexmin_f32<0x114>(bvv, bjj);
            dpp_lexmin_f32<0x118>(bvv, bjj);
            dpp_lexmin_f32<0x142>(bvv, bjj);
            dpp_lexmin_f32<0x143>(bvv, bjj);
            if (lane == 63)
                sm.c.rmin[o * 2 + (wave & 1)] =
                    ((unsigned long long)__float_as_uint(bvv) << 32) | (unsigned)bjj;
        }
        __syncthreads();
        if (tid < OO) {
            unsigned long long r0 = sm.c.rmin[tid * 2 + 0];
            unsigned long long r1 = sm.c.rmin[tid * 2 + 1];
            rowmins[((size_t)b * NTILE + tile) * OO + tid] = r0 < r1 ? r0 : r1;
        }
        __syncthreads();   // drains vmcnt(0): all global stores issued
        if (tid == 0)      // agent-scope release: cost+rowmins visible first
            __hip_atomic_fetch_add(&cnt[b], 1, __ATOMIC_RELEASE,
                                   __HIP_MEMORY_SCOPE_AGENT);
    }

    if (tile != 0) return;   // 480 producer-only blocks exit

    // ============ Phase 2 (tile-0 blocks): wait for siblings ============
    if (tid == 0) {
        while (__hip_atomic_load(&cnt[b], __ATOMIC_ACQUIRE,
                                 __HIP_MEMORY_SCOPE_AGENT) < NTILE)
            __builtin_amdgcn_s_sleep(2);
    }
    __syncthreads();   // all threads see post-acquire state

    // ======================= Phase 3: LSA =======================
    const float* cb = cost + (size_t)b * OO * TT;
    const int jbase = tid * SLOTS;

    double v_[SLOTS];
    double key[SLOTS];
    #pragma unroll
    for (int s = 0; s < SLOTS; ++s) v_[s] = 0.0;

    // ---- Phase A: u = row minima (combine the 16 tile results) ----
    if (tid < OO) {
        const unsigned long long* p = rowmins + (size_t)b * NTILE * OO + tid;
        unsigned long long best = p[0];
        #pragma unroll
        for (int t = 1; t < NTILE; ++t) {
            unsigned long long x = p[t * OO];
            if (x < best) best = x;
        }
        sm.l.u[tid] = (double)__uint_as_float((unsigned)(best >> 32));
        sm.l.amin[tid] = (int)(best & 0xFFFFFFFFull);
        sm.l.col4row[tid] = -1;
    }
    for (int j = tid; j < TT; j += NT) { sm.l.row4col[j] = -1; sm.l.claim[j] = 0x7FFFFFFF; }
    __syncthreads();

    // ---- Phase B: greedy tight pre-assignment (lowest row wins) ----
    if (tid < OO) atomicMin(&sm.l.claim[sm.l.amin[tid]], tid);
    __syncthreads();
    if (tid < OO) {
        int j = sm.l.amin[tid];
        if (sm.l.claim[j] == tid) { sm.l.col4row[tid] = j; sm.l.row4col[j] = tid; }
    }
    __syncthreads();

    // ---- Phase C: urow init + free-row list ----
    for (int j = tid; j < TT; j += NT) {
        int r = sm.l.row4col[j];
        URow t; t.row = r; t.u = (r >= 0) ? sm.l.u[r] : 0.0; t.pad = 0;
        sm.l.urow[j] = t;
    }
    if (tid < OO) sm.l.flag[tid] = (sm.l.col4row[tid] < 0) ? 1 : 0;
    __syncthreads();
    if (tid < OO && sm.l.flag[tid]) {
        int rank = 0;
        for (int o = 0; o < tid; ++o) rank += sm.l.flag[o];
        sm.l.freelist[rank] = tid;
    }
    if (tid == 0) {
        int nf = 0;
        for (int o = 0; o < OO; ++o) nf += sm.l.flag[o];
        sm.l.nfree = nf;
    }
    __syncthreads();
    int nfree = sm.l.nfree;

    // root-row prefetch for the first Dijkstra
    float4 pf0, pf1;
    if (nfree > 0) {
        const float* rr = cb + (size_t)sm.l.freelist[0] * TT + jbase;
        pf0 = *(const float4*)rr;
        pf1 = *(const float4*)(rr + 4);
    }

    // ---- Phase D: Dijkstra SAP ----
    int par = 0;
    for (int fi = 0; fi < nfree; ++fi) {
        int cur = sm.l.freelist[fi];

        #pragma unroll
        for (int s = 0; s < SLOTS; ++s) key[s] = INFINITY;
        int selbits = 0;
        double mv = 0.0;
        int i = cur, jc = -1;
        double ui = sm.l.u[cur];
        float4 c0 = pf0, c1 = pf1;
        int L = 0, sink;

        while (true) {
            float cv[SLOTS] = {c0.x, c0.y, c0.z, c0.w, c1.x, c1.y, c1.z, c1.w};
            double D = ui - mv;   // wave-uniform; one dependent op hoisted

            double bv = INFINITY;
            int bj = TT;
            #pragma unroll
            for (int s = 0; s < SLOTS; ++s) {
                if (!((selbits >> s) & 1)) {
                    double r = ((double)cv[s] - D) - v_[s];
                    if (r < key[s]) {
                        key[s] = r;
                        P2 p; p.i = i; p.j = jc;
                        sm.l.path2[s * NT + tid] = p;
                    }
                    double kk = key[s];
                    if (kk < bv) { bv = kk; bj = jbase + s; }
                }
            }
            dpp_lexmin<0x111>(bv, bj);
            dpp_lexmin<0x112>(bv, bj);
            dpp_lexmin<0x114>(bv, bj);
            dpp_lexmin<0x118>(bv, bj);
            dpp_lexmin<0x142>(bv, bj);
            dpp_lexmin<0x143>(bv, bj);
            int rlo = __builtin_amdgcn_readlane(__double2loint(bv), 63);
            int rhi = __builtin_amdgcn_readlane(__double2hiint(bv), 63);
            double wv = __hiloint2double(rhi, rlo);
            int wj = __builtin_amdgcn_readlane(bj, 63);

            // Pre-barrier: fold this wave's candidate urow in (urow is
            // read-only during the while loop) and speculatively prefetch
            // the candidate's cost row.
            URow uwv = sm.l.urow[wj];          // wave-uniform b128 read
            float4 s0, s1;
            if (uwv.row >= 0) {
                const float* sr = cb + (size_t)uwv.row * TT + jbase;
                s0 = *(const float4*)sr;
                s1 = *(const float4*)(sr + 4);
            }

            par ^= 1;
            if (lane == 0) {
                Cand c; c.v = wv; c.u = uwv.u; c.j = wj; c.row = uwv.row;
                sm.l.cand[par][wave] = c;
            }
            __syncthreads();

            Cand cc0 = sm.l.cand[par][0];
            Cand cc1 = sm.l.cand[par][1];
            Cand cc2 = sm.l.cand[par][2];
            Cand cc3 = sm.l.cand[par][3];
            double MV = cc0.v; int BJ = cc0.j; int WR = cc0.row; double WU = cc0.u;
            if (cc1.v < MV || (cc1.v == MV && cc1.j < BJ)) { MV = cc1.v; BJ = cc1.j; WR = cc1.row; WU = cc1.u; }
            if (cc2.v < MV || (cc2.v == MV && cc2.j < BJ)) { MV = cc2.v; BJ = cc2.j; WR = cc2.row; WU = cc2.u; }
            if (cc3.v < MV || (cc3.v == MV && cc3.j < BJ)) { MV = cc3.v; BJ = cc3.j; WR = cc3.row; WU = cc3.u; }
            mv = MV;
            if ((BJ >> 3) == tid) selbits |= 1 << (BJ & 7);
            if (tid == 0) sm.l.selj[L] = BJ;

            if (WR < 0) { sink = BJ; break; }
            if (tid == 0) { sm.l.selm[L] = MV; sm.l.selrow[L] = WR; }
            i = WR; ui = WU; jc = BJ;
            L++;
            if (BJ == wj) {            // my wave's candidate won: row in flight
                c0 = s0; c1 = s1;
            } else {
                const float* crow = cb + (size_t)i * TT + jbase;
                c0 = *(const float4*)crow;
                c1 = *(const float4*)(crow + 4);
            }
        }

        // prefetch next Dijkstra's root row (off the critical path)
        if (fi + 1 < nfree) {
            const float* rr = cb + (size_t)sm.l.freelist[fi + 1] * TT + jbase;
            pf0 = *(const float4*)rr;
            pf1 = *(const float4*)(rr + 4);
        }

        double M = mv;
        #pragma unroll
        for (int s = 0; s < SLOTS; ++s)
            if ((selbits >> s) & 1) v_[s] = v_[s] - (M - key[s]);
        for (int k = tid; k < L; k += NT)
            sm.l.u[sm.l.selrow[k]] = sm.l.u[sm.l.selrow[k]] + (M - sm.l.selm[k]);
        if (tid == 0) {
            sm.l.u[cur] = sm.l.u[cur] + M;
            int j = sink;
            while (true) {
                P2 p = sm.l.path2[(j & 7) * NT + (j >> 3)];
                int ii = p.i;
                sm.l.row4col[j] = ii;
                sm.l.col4row[ii] = j;
                if (ii == cur) break;
                j = p.j;
            }
        }
        __syncthreads();
        if (tid <= L) {
            int j = sm.l.selj[tid];
            int r = sm.l.row4col[j];
            URow t; t.u = sm.l.u[r]; t.row = r; t.pad = 0;
            sm.l.urow[j] = t;
        }
        __syncthreads();
    }

    // order = argsort(col4row); pred_idx = col4row[order]; tgt_idx = order
    if (tid < OO) {
        int my = sm.l.col4row[tid];
        int rank = 0;
        for (int o = 0; o < OO; ++o) rank += (sm.l.col4row[o] < my) ? 1 : 0;
        out[(size_t)b * OO + rank] = my;         // pred_idx
        out[(size_t)(BB + b) * OO + rank] = tid; // tgt_idx
    }
}

// ---------------------------------------------------------------------------
extern "C" void kernel_launch(void* const* d_in, const int* in_sizes, int n_in,
                              void* d_out, int out_size, void* d_ws, size_t ws_size,
                              hipStream_t stream) {
    const float* pred_bboxes = (const float*)d_in[0];    // [B,T,4]
    const float* target_bboxes = (const float*)d_in[1];  // [B,O,4]
    const float* pred_classes = (const float*)d_in[2];   // [B,T,C]
    const int* target_classes = (const int*)d_in[3];     // [B,O]
    int* out = (int*)d_out;                              // [2,B,O] int32

    float* cost = (float*)d_ws;  // [B][O][T] fp32 (32 MB)
    unsigned long long* rowmins =
        (unsigned long long*)(cost + (size_t)BB * OO * TT);  // [B][NTILE][O]
    int* cnt = (int*)(rowmins + (size_t)BB * NTILE * OO);    // [B]

    (void)hipMemsetAsync(cnt, 0, BB * sizeof(int), stream);  // d_ws is 0xAA-poisoned

    hung_fused_kernel<<<BB * NTILE, NT, 0, stream>>>(
        pred_bboxes, target_bboxes, pred_classes, target_classes,
        cost, rowmins, cnt, out);
}

// Round 13
// 258.933 us; speedup vs baseline: 1.0118x; 1.0118x over previous
//
#include <hip/hip_runtime.h>
#include <math.h>
#include <float.h>

// Problem dims (fixed by setup_inputs)
#define BB 32
#define TT 2048
#define OO 128
#define CC 80
#define EPSF 1e-7f
#define NT 256
#define SLOTS 8           // columns per thread in LSA
#define CPAD 81           // LDS class-row stride: 81%32=17, gcd(17,32)=1 -> conflict-free
#define TPT 128           // tokens per cost tile
#define NTILE 16          // cost t-tiles (TT/TPT)

typedef float vf4 __attribute__((ext_vector_type(4)));   // native vec for nontemporal

struct alignas(16) URow { double u; int row; int pad; };   // {u[row4col[j]], row4col[j]}
struct alignas(8)  P2   { int i; int j; };                 // path row, its prior column
struct alignas(16) Cand { double v; double u; int j; int row; };  // +urow folded in

// DPP lexicographic-min (val,idx): incoming lanes aggregate strictly-lower
// column ranges -> (tv <= bv) == first-index tie-break. Identity {+inf, MAX}.
template<int CTRL>
__device__ __forceinline__ void dpp_lexmin(double& bv, int& bj) {
    int lo = __double2loint(bv), hi = __double2hiint(bv);
    int tlo = __builtin_amdgcn_update_dpp(0, lo, CTRL, 0xF, 0xF, false);
    int thi = __builtin_amdgcn_update_dpp(0x7FF00000, hi, CTRL, 0xF, 0xF, false);
    int tj  = __builtin_amdgcn_update_dpp(0x7FFFFFFF, bj, CTRL, 0xF, 0xF, false);
    double tv = __hiloint2double(thi, tlo);
    if (tv <= bv) { bv = tv; bj = tj; }
}

// f32 (val,idx) lexmin for the cost phase's row-min reduction.
template<int CTRL>
__device__ __forceinline__ void dpp_lexmin_f32(float& bv, int& bj) {
    int tlo = __builtin_amdgcn_update_dpp(0x7F800000, __float_as_int(bv), CTRL, 0xF, 0xF, false);
    int tj  = __builtin_amdgcn_update_dpp(0x7FFFFFFF, bj, CTRL, 0xF, 0xF, false);
    float tv = __int_as_float(tlo);
    if (tv < bv || (tv == bv && tj < bj)) { bv = tv; bj = tj; }
}

// LDS is phase-exclusive: cost staging first, LSA state after.
// Union max ~69 KB -> 2 blocks/CU (the occupancy lever for the cost phase).
union SM {
    struct {
        float  xv[TPT * CPAD];                     // 41472 B
        float4 box[OO];                            // {x1,y1,x2,y2}
        float2 wt[OO];                             // {w2h2, tc-as-float-bits}
        unsigned long long rmin[OO * 2];
    } c;
    struct {
        URow   urow[TT];
        P2     path2[TT];                          // swizzled
        int    row4col[TT];
        int    claim[TT];
        int    col4row[OO];
        double u[OO];
        int    amin[OO];
        int    flag[OO];
        int    freelist[OO];
        int    selj[OO + 8];
        double selm[OO + 8];
        int    selrow[OO + 8];
        Cand   cand[2][4];
        int    nfree;
    } l;
};

// ---------------------------------------------------------------------------
// Fused kernel, XCD-matched mapping: b = bx&31, tile = bx>>5 (all of batch
// b's blocks share bx%8 -> same XCD under round-robin). 512 producer blocks
// each do a 128-token cost tile (2 threads/token); tile-0 blocks then
// acquire-spin on cnt[b]==16 and run the JV LSA (greedy tight pre-assignment
// + Dijkstra SAP with pre-barrier urow fold-in; NO speculative row prefetch
// — r12 A/B showed it regresses).
// ---------------------------------------------------------------------------
__global__ __launch_bounds__(NT) void hung_fused_kernel(
    const float* __restrict__ pb, const float* __restrict__ tb,
    const float* __restrict__ cls, const int* __restrict__ tcls,
    float* __restrict__ cost, unsigned long long* __restrict__ rowmins,
    int* __restrict__ cnt, int* __restrict__ out) {
#pragma clang fp contract(off)
    __shared__ SM sm;

    int bx = blockIdx.x;
    int b = bx & 31;
    int tile = bx >> 5;
    int t0 = tile * TPT;
    int tid = threadIdx.x;
    int lane = tid & 63;
    int wave = tid >> 6;
    int tok = tid & (TPT - 1);
    int oh = tid >> 7;           // o-half: 0 -> o in [0,64), 1 -> [64,128)

    // ======================= Phase 1: cost tile =======================
    {
        // stage class tile (nontemporal: read-once)
        const float* cbase = cls + ((size_t)b * TT + t0) * CC;
        #pragma unroll
        for (int k = 0; k < (TPT * CC) / (NT * 4); ++k) {   // 10 iters
            int idx4 = (k * NT + tid) * 4;
            vf4 vv = __builtin_nontemporal_load((const vf4*)(cbase + idx4));
            int r = idx4 / CC;
            int c = idx4 - r * CC;
            float* dst = &sm.c.xv[r * CPAD + c];
            dst[0] = vv.x; dst[1] = vv.y; dst[2] = vv.z; dst[3] = vv.w;
        }
        if (tid < OO) {
            float4 tbox = ((const float4*)tb)[b * OO + tid];
            float x1 = tbox.x - tbox.z / 2.f;
            float y1 = tbox.y - tbox.w / 2.f;
            float x2 = tbox.x + tbox.z / 2.f;
            float y2 = tbox.y + tbox.w / 2.f;
            float4 bb; bb.x = x1; bb.y = y1; bb.z = x2; bb.w = y2;
            sm.c.box[tid] = bb;
            float w2 = x2 - x1;
            float h2 = (y2 - y1) + EPSF;
            float2 wt; wt.x = w2 * h2;
            wt.y = __int_as_float(tcls[b * OO + tid]);
            sm.c.wt[tid] = wt;
        }
        __syncthreads();

        size_t bt = (size_t)b * TT + t0 + tok;
        float4 pbox = ((const float4*)pb)[bt];
        float b1x1 = pbox.x - pbox.z / 2.f;
        float b1y1 = pbox.y - pbox.w / 2.f;
        float b1x2 = pbox.x + pbox.z / 2.f;
        float b1y2 = pbox.y + pbox.w / 2.f;
        float w1 = b1x2 - b1x1;
        float h1 = (b1y2 - b1y1) + EPSF;
        float w1h1 = w1 * h1;

        // softmax normalizers (sequential op order -> bit-identical to ref)
        const float* xr = &sm.c.xv[tok * CPAD];
        float m = xr[0];
        #pragma unroll
        for (int c = 1; c < CC; ++c) m = fmaxf(m, xr[c]);
        float ssum = 0.f;
        #pragma unroll
        for (int c = 0; c < CC; ++c) ssum += expf(xr[c] - m);
        float ls = logf(ssum);

        float* cbt = cost + (size_t)b * OO * TT + t0;
        for (int k = 0; k < OO / 2; ++k) {
            int o = oh * (OO / 2) + k;
            float4 bb = sm.c.box[o];        // one b128 broadcast per wave
            float2 wt = sm.c.wt[o];
            float b2x1 = bb.x, b2y1 = bb.y, b2x2 = bb.z, b2y2 = bb.w;
            float iw = fminf(b1x2, b2x2) - fmaxf(b1x1, b2x1);
            float ih = fminf(b1y2, b2y2) - fmaxf(b1y1, b2y1);
            iw = fmaxf(iw, 0.f);
            ih = fmaxf(ih, 0.f);
            float inter = iw * ih;
            float uni = ((w1h1 + wt.x) - inter) + EPSF;
            float iou = inter / uni;
            float cw = fmaxf(b1x2, b2x2) - fminf(b1x1, b2x1);
            float ch = fmaxf(b1y2, b2y2) - fminf(b1y1, b2y1);
            float c_area = (cw * ch) + EPSF;
            float giou = iou - (c_area - uni) / c_area;
            float bbox_loss = 1.0f - giou;

            float xc = xr[__float_as_int(wt.y)];   // conflict-free (stride 81)
            float shifted = xc - m;
            float cls_neg = -(shifted - ls);

            float cval = bbox_loss + cls_neg;
            cbt[(size_t)o * TT + tok] = cval;

            // per-(b,o) wave min/argmin over this wave's 64 tokens
            float bvv = cval;
            int bjj = t0 + tok;
            dpp_lexmin_f32<0x111>(bvv, bjj);
            dpp_lexmin_f32<0x112>(bvv, bjj);
            dpp_lexmin_f32<0x114>(bvv, bjj);
            dpp_lexmin_f32<0x118>(bvv, bjj);
            dpp_lexmin_f32<0x142>(bvv, bjj);
            dpp_lexmin_f32<0x143>(bvv, bjj);
            if (lane == 63)
                sm.c.rmin[o * 2 + (wave & 1)] =
                    ((unsigned long long)__float_as_uint(bvv) << 32) | (unsigned)bjj;
        }
        __syncthreads();
        if (tid < OO) {
            unsigned long long r0 = sm.c.rmin[tid * 2 + 0];
            unsigned long long r1 = sm.c.rmin[tid * 2 + 1];
            rowmins[((size_t)b * NTILE + tile) * OO + tid] = r0 < r1 ? r0 : r1;
        }
        __syncthreads();   // drains vmcnt(0): all global stores issued
        if (tid == 0)      // agent-scope release: cost+rowmins visible first
            __hip_atomic_fetch_add(&cnt[b], 1, __ATOMIC_RELEASE,
                                   __HIP_MEMORY_SCOPE_AGENT);
    }

    if (tile != 0) return;   // 480 producer-only blocks exit

    // ============ Phase 2 (tile-0 blocks): wait for siblings ============
    if (tid == 0) {
        while (__hip_atomic_load(&cnt[b], __ATOMIC_ACQUIRE,
                                 __HIP_MEMORY_SCOPE_AGENT) < NTILE)
            __builtin_amdgcn_s_sleep(2);
    }
    __syncthreads();   // all threads see post-acquire state

    // ======================= Phase 3: LSA =======================
    const float* cb = cost + (size_t)b * OO * TT;
    const int jbase = tid * SLOTS;

    double v_[SLOTS];
    double key[SLOTS];
    #pragma unroll
    for (int s = 0; s < SLOTS; ++s) v_[s] = 0.0;

    // ---- Phase A: u = row minima (combine the 16 tile results) ----
    if (tid < OO) {
        const unsigned long long* p = rowmins + (size_t)b * NTILE * OO + tid;
        unsigned long long best = p[0];
        #pragma unroll
        for (int t = 1; t < NTILE; ++t) {
            unsigned long long x = p[t * OO];
            if (x < best) best = x;
        }
        sm.l.u[tid] = (double)__uint_as_float((unsigned)(best >> 32));
        sm.l.amin[tid] = (int)(best & 0xFFFFFFFFull);
        sm.l.col4row[tid] = -1;
    }
    for (int j = tid; j < TT; j += NT) { sm.l.row4col[j] = -1; sm.l.claim[j] = 0x7FFFFFFF; }
    __syncthreads();

    // ---- Phase B: greedy tight pre-assignment (lowest row wins) ----
    if (tid < OO) atomicMin(&sm.l.claim[sm.l.amin[tid]], tid);
    __syncthreads();
    if (tid < OO) {
        int j = sm.l.amin[tid];
        if (sm.l.claim[j] == tid) { sm.l.col4row[tid] = j; sm.l.row4col[j] = tid; }
    }
    __syncthreads();

    // ---- Phase C: urow init + free-row list ----
    for (int j = tid; j < TT; j += NT) {
        int r = sm.l.row4col[j];
        URow t; t.row = r; t.u = (r >= 0) ? sm.l.u[r] : 0.0; t.pad = 0;
        sm.l.urow[j] = t;
    }
    if (tid < OO) sm.l.flag[tid] = (sm.l.col4row[tid] < 0) ? 1 : 0;
    __syncthreads();
    if (tid < OO && sm.l.flag[tid]) {
        int rank = 0;
        for (int o = 0; o < tid; ++o) rank += sm.l.flag[o];
        sm.l.freelist[rank] = tid;
    }
    if (tid == 0) {
        int nf = 0;
        for (int o = 0; o < OO; ++o) nf += sm.l.flag[o];
        sm.l.nfree = nf;
    }
    __syncthreads();
    int nfree = sm.l.nfree;

    // root-row prefetch for the first Dijkstra
    float4 pf0, pf1;
    if (nfree > 0) {
        const float* rr = cb + (size_t)sm.l.freelist[0] * TT + jbase;
        pf0 = *(const float4*)rr;
        pf1 = *(const float4*)(rr + 4);
    }

    // ---- Phase D: Dijkstra SAP ----
    int par = 0;
    for (int fi = 0; fi < nfree; ++fi) {
        int cur = sm.l.freelist[fi];

        #pragma unroll
        for (int s = 0; s < SLOTS; ++s) key[s] = INFINITY;
        int selbits = 0;
        double mv = 0.0;
        int i = cur, jc = -1;
        double ui = sm.l.u[cur];
        float4 c0 = pf0, c1 = pf1;
        int L = 0, sink;

        while (true) {
            float cv[SLOTS] = {c0.x, c0.y, c0.z, c0.w, c1.x, c1.y, c1.z, c1.w};
            double D = ui - mv;   // wave-uniform; one dependent op hoisted

            double bv = INFINITY;
            int bj = TT;
            #pragma unroll
            for (int s = 0; s < SLOTS; ++s) {
                if (!((selbits >> s) & 1)) {
                    double r = ((double)cv[s] - D) - v_[s];
                    if (r < key[s]) {
                        key[s] = r;
                        P2 p; p.i = i; p.j = jc;
                        sm.l.path2[s * NT + tid] = p;
                    }
                    double kk = key[s];
                    if (kk < bv) { bv = kk; bj = jbase + s; }
                }
            }
            dpp_lexmin<0x111>(bv, bj);
            dpp_lexmin<0x112>(bv, bj);
            dpp_lexmin<0x114>(bv, bj);
            dpp_lexmin<0x118>(bv, bj);
            dpp_lexmin<0x142>(bv, bj);
            dpp_lexmin<0x143>(bv, bj);
            int rlo = __builtin_amdgcn_readlane(__double2loint(bv), 63);
            int rhi = __builtin_amdgcn_readlane(__double2hiint(bv), 63);
            double wv = __hiloint2double(rhi, rlo);
            int wj = __builtin_amdgcn_readlane(bj, 63);

            // Pre-barrier urow fold-in: each wave reads its own candidate's
            // urow entry (read-only during the while loop); the LDS latency
            // overlaps other waves' barrier arrival.
            URow uwv = sm.l.urow[wj];          // wave-uniform b128 read

            par ^= 1;
            if (lane == 0) {
                Cand c; c.v = wv; c.u = uwv.u; c.j = wj; c.row = uwv.row;
                sm.l.cand[par][wave] = c;
            }
            __syncthreads();

            Cand cc0 = sm.l.cand[par][0];
            Cand cc1 = sm.l.cand[par][1];
            Cand cc2 = sm.l.cand[par][2];
            Cand cc3 = sm.l.cand[par][3];
            double MV = cc0.v; int BJ = cc0.j; int WR = cc0.row; double WU = cc0.u;
            if (cc1.v < MV || (cc1.v == MV && cc1.j < BJ)) { MV = cc1.v; BJ = cc1.j; WR = cc1.row; WU = cc1.u; }
            if (cc2.v < MV || (cc2.v == MV && cc2.j < BJ)) { MV = cc2.v; BJ = cc2.j; WR = cc2.row; WU = cc2.u; }
            if (cc3.v < MV || (cc3.v == MV && cc3.j < BJ)) { MV = cc3.v; BJ = cc3.j; WR = cc3.row; WU = cc3.u; }
            mv = MV;
            if ((BJ >> 3) == tid) selbits |= 1 << (BJ & 7);
            if (tid == 0) sm.l.selj[L] = BJ;

            if (WR < 0) { sink = BJ; break; }
            if (tid == 0) { sm.l.selm[L] = MV; sm.l.selrow[L] = WR; }
            i = WR; ui = WU; jc = BJ;
            L++;
            const float* crow = cb + (size_t)i * TT + jbase;
            c0 = *(const float4*)crow;
            c1 = *(const float4*)(crow + 4);
        }

        // prefetch next Dijkstra's root row (off the critical path)
        if (fi + 1 < nfree) {
            const float* rr = cb + (size_t)sm.l.freelist[fi + 1] * TT + jbase;
            pf0 = *(const float4*)rr;
            pf1 = *(const float4*)(rr + 4);
        }

        double M = mv;
        #pragma unroll
        for (int s = 0; s < SLOTS; ++s)
            if ((selbits >> s) & 1) v_[s] = v_[s] - (M - key[s]);
        for (int k = tid; k < L; k += NT)
            sm.l.u[sm.l.selrow[k]] = sm.l.u[sm.l.selrow[k]] + (M - sm.l.selm[k]);
        if (tid == 0) {
            sm.l.u[cur] = sm.l.u[cur] + M;
            int j = sink;
            while (true) {
                P2 p = sm.l.path2[(j & 7) * NT + (j >> 3)];
                int ii = p.i;
                sm.l.row4col[j] = ii;
                sm.l.col4row[ii] = j;
                if (ii == cur) break;
                j = p.j;
            }
        }
        __syncthreads();
        if (tid <= L) {
            int j = sm.l.selj[tid];
            int r = sm.l.row4col[j];
            URow t; t.u = sm.l.u[r]; t.row = r; t.pad = 0;
            sm.l.urow[j] = t;
        }
        __syncthreads();
    }

    // order = argsort(col4row); pred_idx = col4row[order]; tgt_idx = order
    if (tid < OO) {
        int my = sm.l.col4row[tid];
        int rank = 0;
        for (int o = 0; o < OO; ++o) rank += (sm.l.col4row[o] < my) ? 1 : 0;
        out[(size_t)b * OO + rank] = my;         // pred_idx
        out[(size_t)(BB + b) * OO + rank] = tid; // tgt_idx
    }
}

// ---------------------------------------------------------------------------
extern "C" void kernel_launch(void* const* d_in, const int* in_sizes, int n_in,
                              void* d_out, int out_size, void* d_ws, size_t ws_size,
                              hipStream_t stream) {
    const float* pred_bboxes = (const float*)d_in[0];    // [B,T,4]
    const float* target_bboxes = (const float*)d_in[1];  // [B,O,4]
    const float* pred_classes = (const float*)d_in[2];   // [B,T,C]
    const int* target_classes = (const int*)d_in[3];     // [B,O]
    int* out = (int*)d_out;                              // [2,B,O] int32

    float* cost = (float*)d_ws;  // [B][O][T] fp32 (32 MB)
    unsigned long long* rowmins =
        (unsigned long long*)(cost + (size_t)BB * OO * TT);  // [B][NTILE][O]
    int* cnt = (int*)(rowmins + (size_t)BB * NTILE * OO);    // [B]

    (void)hipMemsetAsync(cnt, 0, BB * sizeof(int), stream);  // d_ws is 0xAA-poisoned

    hung_fused_kernel<<<BB * NTILE, NT, 0, stream>>>(
        pred_bboxes, target_bboxes, pred_classes, target_classes,
        cost, rowmins, cnt, out);
}